// Round 6
// baseline (1063.406 us; speedup 1.0000x reference)
//
#include <hip/hip_runtime.h>

typedef unsigned short u16;
typedef unsigned char  u8;
typedef unsigned int   u32;
typedef unsigned long long u64;

typedef __attribute__((ext_vector_type(8)))  short short8;
typedef __attribute__((ext_vector_type(4)))  short short4v;
typedef __attribute__((ext_vector_type(4)))  float float4v;

#define NB 8
#define NC 512
#define NT 4096
#define NO 1536
#define SCALE_QK 0.04419417382415922f   /* 512^-0.5 */
#define LOG2E_   1.4426950408889634f

__device__ inline u16 f2b(float f){
  u32 u = __builtin_bit_cast(u32, f);
  u += 0x7fffu + ((u >> 16) & 1u);
  return (u16)(u >> 16);
}
__device__ inline float b2f(short s){
  return __builtin_bit_cast(float, (u32)((u16)s) << 16);
}
__device__ inline u8 f2fp8(float f){
  u32 r = (u32)__builtin_amdgcn_cvt_pk_fp8_f32(f, f, 0, 0);
  return (u8)(r & 0xffu);
}

typedef __attribute__((address_space(1))) const unsigned int as1c_uint;
typedef __attribute__((address_space(3))) unsigned int as3_uint;

__device__ inline void gload16(const void* g, void* l){
  // each lane: 16B global (per-lane addr) -> LDS at (wave-uniform base + lane*16)
  __builtin_amdgcn_global_load_lds((as1c_uint*)g, (as3_uint*)l, 16, 0, 0);
}

__device__ inline short8 ld8pair(const u16* p){
  short4v a = *(const short4v*)(p);
  short4v b = *(const short4v*)(p + 4);
  return __builtin_shufflevector(a, b, 0,1,2,3,4,5,6,7);
}

// ---------------- k0: f32 -> bf16 weight convert ----------------
__global__ void k_cvt(const float* __restrict__ src, u16* __restrict__ dst, int n){
  int i = blockIdx.x*256 + threadIdx.x;
  if (i < n) dst[i] = f2b(src[i]);
}

// ---------------- k1: groupnorm stats (mean, rstd per (b,g)) ----------------
__global__ void k_stats(const float* __restrict__ x, float* __restrict__ stats){
  int bg = blockIdx.x;           // 256 = 8*32
  int tid = threadIdx.x;
  const float4* p = (const float4*)(x + (size_t)bg*65536);
  float s = 0.f, q = 0.f;
  for (int i=0;i<64;i++){
    float4 v = p[i*256 + tid];
    s += v.x+v.y+v.z+v.w;
    q += v.x*v.x + v.y*v.y + v.z*v.z + v.w*v.w;
  }
  __shared__ float ls[256], lq[256];
  ls[tid]=s; lq[tid]=q; __syncthreads();
  for (int off=128; off>0; off>>=1){
    if (tid < off){ ls[tid]+=ls[tid+off]; lq[tid]+=lq[tid+off]; }
    __syncthreads();
  }
  if (tid==0){
    float mean = ls[0]*(1.f/65536.f);
    float var  = lq[0]*(1.f/65536.f) - mean*mean;
    stats[bg*2]   = mean;
    stats[bg*2+1] = rsqrtf(var + 1e-5f);
  }
}

// ---------------- k2: GN apply + transpose (b,c,t)f32 -> (b,t,c)bf16 ----------------
__global__ void k_gn_apply(const float* __restrict__ x, const float* __restrict__ stats,
                           const float* __restrict__ gw, const float* __restrict__ gb,
                           u16* __restrict__ h){
  __shared__ u16 lt[64*65];
  int b = blockIdx.z, c0 = blockIdx.y*64, t0 = blockIdx.x*64;
  int tid = threadIdx.x;
  for (int it=0; it<16; it++){
    int idx = it*256 + tid;
    int cl = idx>>6, tl = idx&63;
    int c = c0 + cl;
    float v = x[((size_t)b*NC + c)*NT + t0 + tl];
    float mean = stats[(b*32 + (c>>4))*2];
    float rstd = stats[(b*32 + (c>>4))*2 + 1];
    float y = (v - mean)*rstd*gw[c] + gb[c];
    lt[cl*65 + tl] = f2b(y);
  }
  __syncthreads();
  for (int it=0; it<16; it++){
    int idx = it*256 + tid;
    int tw = idx>>6, cw = idx&63;
    h[((size_t)b*NT + t0 + tw)*NC + c0 + cw] = lt[cw*65 + tw];
  }
}

// ---------------- GEMM helpers: 128x128 tile, BK=64, 4 waves ----------------
__device__ inline void stage128(const u16* gbase, u16* lbuf, int w, int l){
  #pragma unroll
  for (int i=0;i<4;i++){
    int r0 = (w*4+i)*8;
    int lr = r0 + (l>>3);
    int gch = (l&7) ^ (lr&7);
    gload16(gbase + (size_t)lr*512 + gch*8, lbuf + r0*64);
  }
}

__device__ inline void tile_mac(const u16* sA, const u16* sB, float4v acc[4][4], int wm, int wn, int l){
  #pragma unroll
  for (int kk=0; kk<2; kk++){
    short8 af[4], bf[4];
    #pragma unroll
    for (int f=0; f<4; f++){
      int rowA = wm + f*16 + (l&15);
      int chA  = (kk*4 + (l>>4)) ^ (rowA&7);
      af[f] = *(const short8*)(sA + rowA*64 + chA*8);
      int rowB = wn + f*16 + (l&15);
      int chB  = (kk*4 + (l>>4)) ^ (rowB&7);
      bf[f] = *(const short8*)(sB + rowB*64 + chB*8);
    }
    #pragma unroll
    for (int fm=0; fm<4; fm++)
      #pragma unroll
      for (int fn=0; fn<4; fn++)
        acc[fm][fn] = __builtin_amdgcn_mfma_f32_16x16x32_bf16(af[fm], bf[fn], acc[fm][fn], 0,0,0);
  }
}

// ---------------- k3: qkv^T GEMM: D[t][o] = sum_c h[t,c]*W[o,c] + bias[o]
//   o < 1024 (q,k): write qkv[t][o] bf16;  o >= 1024 (v): write vct[c=o-1024][t] fp8
__global__ __launch_bounds__(256,2) void k_qkv_gemm(const u16* __restrict__ h, const u16* __restrict__ wq,
                                                    const float* __restrict__ qb, u16* __restrict__ qkv,
                                                    u8* __restrict__ vct){
  __shared__ __align__(16) u16 lA[2][8192];
  __shared__ __align__(16) u16 lB[2][8192];
  int b = blockIdx.z, t0 = blockIdx.y*128, o0 = blockIdx.x*128;
  int tid = threadIdx.x, w = tid>>6, l = tid&63;
  int wm = (w&1)*64, wn = (w>>1)*64;
  float4v acc[4][4];
  #pragma unroll
  for (int i=0;i<4;i++)
    #pragma unroll
    for (int j=0;j<4;j++)
      #pragma unroll
      for (int e=0;e<4;e++) acc[i][j][e] = 0.f;
  const u16* Ab = h  + ((size_t)b*NT + t0)*NC;
  const u16* Bb = wq + (size_t)o0*NC;
  stage128(Ab, lA[0], w, l);
  stage128(Bb, lB[0], w, l);
  __syncthreads();
  for (int it=0; it<8; it++){
    int cur = it&1;
    if (it < 7){
      stage128(Ab + (it+1)*64, lA[cur^1], w, l);
      stage128(Bb + (it+1)*64, lB[cur^1], w, l);
    }
    tile_mac(lA[cur], lB[cur], acc, wm, wn, l);
    __syncthreads();
  }
  u16* ep = ((w < 2) ? (u16*)lA : (u16*)lB) + (w&1)*4352;
  if (o0 < 1024){
    #pragma unroll
    for (int fn=0; fn<4; fn++){
      float bs = qb[o0 + wn + fn*16 + (l&15)];
      #pragma unroll
      for (int fm=0; fm<4; fm++)
        #pragma unroll
        for (int r=0; r<4; r++){
          int tl_ = fm*16 + (l>>4)*4 + r;
          int ol_ = fn*16 + (l&15);
          ep[tl_*68 + ol_] = f2b(acc[fm][fn][r] + bs);
        }
    }
    __syncthreads();
    #pragma unroll
    for (int i=0;i<8;i++){
      int r  = i*8 + (l>>3);
      int c8 = (l&7)*8;
      short8 v8 = ld8pair(ep + r*68 + c8);
      *(short8*)(qkv + ((size_t)b*NT + t0 + wm + r)*NO + o0 + wn + c8) = v8;
    }
  } else {
    #pragma unroll
    for (int fn=0; fn<4; fn++){
      float bs = qb[o0 + wn + fn*16 + (l&15)];
      #pragma unroll
      for (int fm=0; fm<4; fm++)
        #pragma unroll
        for (int r=0; r<4; r++){
          int ol_ = fn*16 + (l&15);
          int tl_ = fm*16 + (l>>4)*4 + r;
          ep[ol_*68 + tl_] = f2b(acc[fm][fn][r] + bs);
        }
    }
    __syncthreads();
    u8* vrow = vct + ((size_t)b*NC + (o0-1024) + wn + l)*NT + t0 + wm;
    #pragma unroll
    for (int i=0;i<8;i++){
      short8 v8 = ld8pair(ep + l*68 + i*8);
      u64 outv = 0;
      #pragma unroll
      for (int jj=0; jj<4; jj++){
        u32 pk = (u32)__builtin_amdgcn_cvt_pk_fp8_f32(b2f(v8[2*jj]), b2f(v8[2*jj+1]), 0, 0);
        outv |= (u64)(pk & 0xffffu) << (16*jj);
      }
      *(u64*)(vrow + i*8) = outv;
    }
  }
}

// ---------------- k5: flash attention: 4 waves/block, t-tile 64, 2 blocks/CU ----------------
// Wave w self-contained for t-rows [w*16,+16): QK^T(bf16) -> in-lane softmax ->
// per-wave fp8 P -> PV(fp8 mfma) over all 512 c. Single-buffered K/V: the stage-wait
// stall is covered by the sibling block on the same SIMDs (independent barrier domain).
__global__ __launch_bounds__(256,2) void k_attn(const u16* __restrict__ qkv, const u8* __restrict__ vct,
                                                u16* __restrict__ at){
  __shared__ __align__(16) u16 lK[32*512];     // 32KB: [32 s][512 c] bf16, chunk-XOR swizzled
  __shared__ __align__(16) u8  lV[512*32];     // 16KB: [512 c][32 s] fp8 rows
  __shared__ __align__(16) u8  lP[4*640];      // per-wave: 16 t x (32 s fp8 + 8 pad) pitch 40
  const int bid = blockIdx.x;
  const int b = bid & 7;                 // batch == XCD (round-robin) for K/V L2 locality
  const int t0 = (bid >> 3) * 64;
  const int tid = threadIdx.x, w = tid>>6, l = tid&63;
  const int l15 = l&15, l4 = l>>4;
  const u16* qkv_b = qkv + (size_t)b*NT*NO;
  const u8*  vct_b = vct + (size_t)b*NC*NT;
  u8* lPw = lP + w*640;

  // Q fragments: wave w owns t-rows t0 + w*16 .. +16
  short8 qf[16];
  {
    const u16* qrow = qkv_b + (size_t)(t0 + w*16 + l15)*NO;        // q at col 0
    #pragma unroll
    for (int ks=0; ks<16; ks++) qf[ks] = *(const short8*)(qrow + ks*32 + l4*8);
  }
  float4v acc[32];                       // D[t=l4*4+r][c = ct*16 + l15]
  #pragma unroll
  for (int i=0;i<32;i++)
    #pragma unroll
    for (int e=0;e<4;e++) acc[i][e] = 0.f;
  float M_r[4] = {-1e30f,-1e30f,-1e30f,-1e30f};
  float L_r[4] = {0.f,0.f,0.f,0.f};      // per-lane partial row-sums (s = l15, 16+l15)

  // ---- prologue: stage tile 0 (K: 8 rows/wave; V: 4 gloads/wave covering [c][32B] rows)
  #pragma unroll
  for (int i=0;i<8;i++){
    int sl = w*8+i;
    gload16(qkv_b + (size_t)sl*NO + 512 + (l ^ (sl&7))*8, &lK[sl*512]);
  }
  #pragma unroll
  for (int i=0;i<4;i++){
    int j = w*4+i;
    gload16(vct_b + (size_t)(j*32 + (l>>1))*NT + (l&1)*16, &lV[j*1024]);
  }
  __syncthreads();

  for (int st=0; st<128; st++){
    // ---- QK^T from lK (bf16)
    float4v Lf0, Lf1;
    #pragma unroll
    for (int e=0;e<4;e++){ Lf0[e]=0.f; Lf1[e]=0.f; }
    #pragma unroll
    for (int ks=0; ks<16; ks++){
      int gch = ks*4 + l4;
      int sA = l15;
      short8 b0 = *(const short8*)(&lK[sA*512 + ((gch ^ (sA&7))*8)]);
      int sB = 16 + l15;
      short8 b1 = *(const short8*)(&lK[sB*512 + ((gch ^ (sB&7))*8)]);
      Lf0 = __builtin_amdgcn_mfma_f32_16x16x32_bf16(qf[ks], b0, Lf0, 0,0,0);
      Lf1 = __builtin_amdgcn_mfma_f32_16x16x32_bf16(qf[ks], b1, Lf1, 0,0,0);
    }

    // ---- in-lane online softmax (row t=l4*4+r; reduce over 16 lanes)
    float v0[4], v1[4], mxA[4];
    bool need = false;
    #pragma unroll
    for (int r=0; r<4; r++){
      v0[r] = Lf0[r]*SCALE_QK; v1[r] = Lf1[r]*SCALE_QK;
      float mx = fmaxf(v0[r], v1[r]);
      mx = fmaxf(mx, __shfl_xor(mx,1));
      mx = fmaxf(mx, __shfl_xor(mx,2));
      mx = fmaxf(mx, __shfl_xor(mx,4));
      mx = fmaxf(mx, __shfl_xor(mx,8));
      mxA[r] = mx;
      need = need || (mx > M_r[r] + 4.0f);
    }
    int nw = __any((int)need);           // wave-uniform (defer-max: P <= e^4 fits e4m3)
    float al[4];
    #pragma unroll
    for (int r=0; r<4; r++){
      float mnew = nw ? fmaxf(M_r[r], mxA[r]) : M_r[r];
      al[r] = nw ? exp2f((M_r[r] - mnew)*LOG2E_) : 1.0f;
      float p0 = exp2f((v0[r] - mnew)*LOG2E_);
      float p1 = exp2f((v1[r] - mnew)*LOG2E_);
      L_r[r] = L_r[r]*al[r] + (p0 + p1);
      M_r[r] = mnew;
      int tl_ = l4*4 + r;
      lPw[tl_*40 + l15]      = f2fp8(p0);
      lPw[tl_*40 + 16 + l15] = f2fp8(p1);
    }

    // ---- PV (fp8): A = P[t=l15][s=l4*8+j], B = V[c=ct*16+l15][s=l4*8+j]
    {
      if (nw){
        #pragma unroll
        for (int ct=0; ct<32; ct++)
          #pragma unroll
          for (int r=0; r<4; r++) acc[ct][r] *= al[r];
      }
      u64 paf = *(const u64*)(lPw + l15*40 + l4*8);
      const u8* vb = &lV[l15*32 + l4*8];
      __builtin_amdgcn_s_setprio(1);
      #pragma unroll
      for (int ct=0; ct<32; ct++){
        u64 vbf = *(const u64*)(vb + ct*512);
        acc[ct] = __builtin_amdgcn_mfma_f32_16x16x32_fp8_fp8((long)paf, (long)vbf, acc[ct], 0,0,0);
      }
      __builtin_amdgcn_s_setprio(0);
    }

    __syncthreads();                     // all waves done reading lK/lV
    if (st < 127){
      const int s1 = st*32 + 32;
      #pragma unroll
      for (int i=0;i<8;i++){
        int sl = w*8+i;
        gload16(qkv_b + (size_t)(s1+sl)*NO + 512 + (l ^ (sl&7))*8, &lK[sl*512]);
      }
      #pragma unroll
      for (int i=0;i<4;i++){
        int j = w*4+i;
        gload16(vct_b + (size_t)(j*32 + (l>>1))*NT + s1 + (l&1)*16, &lV[j*1024]);
      }
    }
    __syncthreads();                     // drains vmcnt: staged K/V visible
  }

  // ---- epilogue: full row-sum (in-reg), divide, write at(b,t,c) bf16
  float iv[4];
  #pragma unroll
  for (int r=0; r<4; r++){
    float s = L_r[r];
    s += __shfl_xor(s,1); s += __shfl_xor(s,2);
    s += __shfl_xor(s,4); s += __shfl_xor(s,8);
    iv[r] = 1.f/s;
  }
  #pragma unroll
  for (int ct=0; ct<32; ct++){
    int cc = ct*16 + l15;
    #pragma unroll
    for (int r=0; r<4; r++){
      int tt = t0 + w*16 + l4*4 + r;
      at[((size_t)b*NT + tt)*NC + cc] = f2b(acc[ct][r]*iv[r]);
    }
  }
}

// ---------------- k6: proj GEMM + bias + residual (f32 out) ----------------
__global__ __launch_bounds__(256,2) void k_proj_res(const u16* __restrict__ wp, const u16* __restrict__ at,
                                                    const float* __restrict__ pb, const float* __restrict__ x,
                                                    float* __restrict__ out){
  __shared__ __align__(16) u16 lA[2][8192];
  __shared__ __align__(16) u16 lB[2][8192];
  int b = blockIdx.z, t0 = blockIdx.x*128, o0 = blockIdx.y*128;
  int tid = threadIdx.x, w = tid>>6, l = tid&63;
  int wm = (w&1)*64, wn = (w>>1)*64;
  float4v acc[4][4];
  #pragma unroll
  for (int i=0;i<4;i++)
    #pragma unroll
    for (int j=0;j<4;j++)
      #pragma unroll
      for (int e=0;e<4;e++) acc[i][j][e] = 0.f;
  const u16* Ab = wp + (size_t)o0*NC;
  const u16* Bb = at + ((size_t)b*NT + t0)*NC;
  stage128(Ab, lA[0], w, l);
  stage128(Bb, lB[0], w, l);
  __syncthreads();
  for (int it=0; it<8; it++){
    int cur = it&1;
    if (it < 7){
      stage128(Ab + (it+1)*64, lA[cur^1], w, l);
      stage128(Bb + (it+1)*64, lB[cur^1], w, l);
    }
    tile_mac(lA[cur], lB[cur], acc, wm, wn, l);
    __syncthreads();
  }
  #pragma unroll
  for (int fm=0; fm<4; fm++)
    #pragma unroll
    for (int r=0; r<4; r++){
      int o = o0 + wm + fm*16 + (l>>4)*4 + r;
      float bs = pb[o];
      #pragma unroll
      for (int fn=0; fn<4; fn++){
        int t = t0 + wn + fn*16 + (l&15);
        size_t idx = ((size_t)b*NC + o)*NT + t;
        out[idx] = acc[fm][fn][r] + bs + x[idx];
      }
    }
}

extern "C" void kernel_launch(void* const* d_in, const int* in_sizes, int n_in,
                              void* d_out, int out_size, void* d_ws, size_t ws_size,
                              hipStream_t stream){
  const float* x    = (const float*)d_in[0];
  const float* gnw  = (const float*)d_in[1];
  const float* gnb  = (const float*)d_in[2];
  const float* qkvw = (const float*)d_in[3];
  const float* qkvb = (const float*)d_in[4];
  const float* pw   = (const float*)d_in[5];
  const float* pb   = (const float*)d_in[6];
  float* out = (float*)d_out;

  char* ws = (char*)d_ws;
  float* stats = (float*)ws;
  u16* h   = (u16*)(ws + 4096);
  u16* qkv = (u16*)(ws + 4096 + 33554432);
  u8*  vct = (u8*)(ws + 4096 + 33554432 + 100663296);
  u16* wqb = (u16*)(ws + 4096 + 33554432 + 100663296 + 33554432);
  u16* wpb = (u16*)(ws + 4096 + 33554432 + 100663296 + 33554432 + 1572864);
  u16* at  = h;

  k_cvt<<<3072, 256, 0, stream>>>(qkvw, wqb, 786432);
  k_cvt<<<1024, 256, 0, stream>>>(pw, wpb, 262144);
  k_stats<<<256, 256, 0, stream>>>(x, stats);
  k_gn_apply<<<dim3(64,8,8), 256, 0, stream>>>(x, stats, gnw, gnb, h);
  k_qkv_gemm<<<dim3(12,32,8), 256, 0, stream>>>(h, wqb, qkvb, qkv, vct);
  k_attn<<<512, 256, 0, stream>>>(qkv, vct, at);
  k_proj_res<<<dim3(32,4,8), 256, 0, stream>>>(wpb, at, pb, x, out);
}